// Round 9
// baseline (298.331 us; speedup 1.0000x reference)
//
#include <hip/hip_runtime.h>
#include <hip/hip_cooperative_groups.h>

// SNN 2048->2048->2048->512, T=100, batch 32, LIF.
// R18 = R17 mega-kernel + three changes:
//  1) grid.sync (512-block single-counter rendezvous ~ 512 serialized
//     same-address atomics, the pathology R17 proved costs ~12ns each)
//     -> custom STRIPED phase gates: 8 per-XCD stripe counters, 64
//     arrivals each, absolute targets from a per-invocation ticket
//     (g_inv>>9). Zero-init device globals, monotonic, no resets ->
//     graph-replay safe. Fences identical to grid.sync (threadfence
//     release before arrive / acquire after pass).
//  2) B-prefetch keep-alives (asm "+v") after each reload: R17's VGPR=60
//     proves the compiler rematerialized the depth-4 loads (true depth-4
//     needs ~95 VGPR). Pin them live.
//  3) T5 s_setprio(1/0) around each kstep's MFMA cluster.
//
// Unified "octet-blocked" layout (pitch MTOT) for spikes AND I:
//   half_idx(v, m) = ((v>>3)*MTOT + m)*8 + (v&7)
// ws regions: R0 [0,13107200) | R1 [+13107200) | I [+26214400)
// Phases: E{enc->R0, convW0->R1} | G0 gemm(R1,R0->I) | S0{scan I->R1,
//   convW1->R0} | G1 | S1{scan I->R0, convW2->R1} | G2(256 blk) | S2->out
#define T_STEPS 100
#define MTOT    3200
#define R0_OFF  0
#define R1_OFF  13107200
#define I_OFF   26214400

typedef _Float16 half8_t __attribute__((ext_vector_type(8)));
typedef _Float16 half4_t __attribute__((ext_vector_type(4)));
typedef float    f32x4   __attribute__((ext_vector_type(4)));

// ================= striped phase gates (device globals) =================
// g_bar[p][s*16]: arrivals of stripe s (blk&7, == XCD) at boundary p.
// Monotonic across invocations; target = 64 * (invocation+1), where
// invocation = (g_inv ticket) >> 9 (512 tickets handed out per launch).
__device__ int g_inv;
__device__ __attribute__((aligned(1024))) int g_bar[6][128];

__device__ __forceinline__ void gate(const int p, const int target) {
    __syncthreads();                       // all waves' stores complete
    if (threadIdx.x == 0) {
        __threadfence();                   // release: flush to coherence
        __hip_atomic_fetch_add(&g_bar[p][(blockIdx.x & 7) * 16], 1,
                               __ATOMIC_RELAXED, __HIP_MEMORY_SCOPE_AGENT);
    }
    if (threadIdx.x < 8) {                 // wave 0 lanes 0..7 poll stripes
        while (__hip_atomic_load(&g_bar[p][threadIdx.x * 16],
                                 __ATOMIC_RELAXED, __HIP_MEMORY_SCOPE_AGENT)
               < target) {
            __builtin_amdgcn_s_sleep(1);
        }
    }
    __syncthreads();                       // whole block saw completion
    __threadfence();                       // acquire: invalidate stale
    __syncthreads();
}

// ============ encode, 512-thr, 64KB XOR-swizzled LDS ====================
__device__ __forceinline__ void encode512_body(
    int blk, const float* __restrict__ x, const float* __restrict__ noise,
    _Float16* __restrict__ spk0, float* __restrict__ out, _Float16* smem)
{
    if (blk == 0 && threadIdx.x == 0) out[16384] = 0.0f;  // runs first
    const int tid  = threadIdx.x;
    const int m0   = blk * 16;
    const int koct = tid & 255;
    const int mlh  = tid >> 8;
    half8_t* lds = (half8_t*)smem;       // [16][256]
    #pragma unroll
    for (int mlq = 0; mlq < 8; ++mlq) {
        const int ml = mlq * 2 + mlh;
        const int m  = m0 + ml;
        const int t = m >> 5, b = m & 31;
        const float4 x1 = *(const float4*)(x + b * 2048 + koct * 8);
        const float4 x2 = *(const float4*)(x + b * 2048 + koct * 8 + 4);
        const float4 n1 = *(const float4*)(noise + (size_t)t * 65536 + b * 2048 + koct * 8);
        const float4 n2 = *(const float4*)(noise + (size_t)t * 65536 + b * 2048 + koct * 8 + 4);
        const float xr[8] = {x1.x,x1.y,x1.z,x1.w,x2.x,x2.y,x2.z,x2.w};
        const float nz[8] = {n1.x,n1.y,n1.z,n1.w,n2.x,n2.y,n2.z,n2.w};
        half8_t sp;
        #pragma unroll
        for (int q = 0; q < 8; ++q) {
            const float r = fminf(fmaxf(xr[q], 0.0f), 1.0f);
            sp[q] = (nz[q] < r) ? (_Float16)1.0f : (_Float16)0.0f;
        }
        lds[ml * 256 + (koct ^ ml)] = sp;
    }
    __syncthreads();
    #pragma unroll
    for (int r = 0; r < 8; ++r) {        // lanes: ml fast -> 256B contiguous
        const int ml  = tid & 15;
        const int oct = r * 32 + (tid >> 4);
        *(half8_t*)(spk0 + ((size_t)oct * MTOT + m0 + ml) * 8)
            = lds[ml * 256 + (oct ^ ml)];
    }
    __syncthreads();                     // smem dead before phase reuse
}

// ============ convw, 512-thr: W fp32 -> fp16 A-frag swizzled ============
__device__ __forceinline__ void convw512_body(
    int cblk, const float* __restrict__ W, _Float16* __restrict__ Wf)
{
    const int koct = threadIdx.x & 255;
    const int rh   = threadIdx.x >> 8;
    #pragma unroll
    for (int r = 0; r < 8; ++r) {
        const int row = cblk * 16 + rh * 8 + r;
        const float* wp = W + (size_t)row * 2048 + koct * 8;
        const float4 f1 = *(const float4*)(wp);
        const float4 f2 = *(const float4*)(wp + 4);
        half8_t h = {(_Float16)f1.x,(_Float16)f1.y,(_Float16)f1.z,(_Float16)f1.w,
                     (_Float16)f2.x,(_Float16)f2.y,(_Float16)f2.z,(_Float16)f2.w};
        const size_t idx = (size_t)(row >> 4) * 32768
                         + ((size_t)((koct >> 2) * 64 + (koct & 3) * 16 + (row & 15))) * 8;
        *(half8_t*)(Wf + idx) = h;
    }
}

// ============ scan, 512-thr, per-BLOCK single atomic ====================
__device__ __forceinline__ void scan512_body(
    int blk, const _Float16* __restrict__ I, const float* __restrict__ bias,
    _Float16* __restrict__ spk_out, float* __restrict__ out,
    const int is_last, float* rsum)
{
    const int gid = blk * 512 + threadIdx.x;
    const int j   = gid & 7;
    const int b   = (gid >> 3) & 31;
    const int oct = gid >> 8;
    const int n   = oct * 8 + j;
    const float bi = bias[n];
    const size_t nbase = (size_t)oct * (MTOT * 8) + j;
    float mem = 0.f, syn = 0.f, osum = 0.f, cnt = 0.f;
    #pragma unroll 4
    for (int t = 0; t < T_STEPS; ++t) {
        const int m = t * 32 + b;
        const float Iv = (float)I[nbase + (size_t)m * 8] + bi;
        syn = syn + (-syn / 5.0f + Iv);
        mem = mem + (-mem / 20.0f + syn);
        const float sv = (mem >= 1.0f) ? 1.0f : 0.0f;
        mem = (sv != 0.0f) ? 0.0f : mem;       // reset
        mem = (mem > 0.0f) ? mem : 0.0f;       // clamp negatives
        cnt += sv; osum += sv;
        if (!is_last) spk_out[nbase + (size_t)m * 8] = (_Float16)sv;
    }
    if (is_last) out[b * 512 + n] = osum * 0.01f;    // mean over T
    // wave reduce -> LDS -> one atomic per block (G12)
    float c = cnt;
    #pragma unroll
    for (int s2 = 1; s2 < 64; s2 <<= 1) c += __shfl_xor(c, s2);
    const int wid = threadIdx.x >> 6;
    if ((threadIdx.x & 63) == 0) rsum[wid] = c;
    __syncthreads();
    if (threadIdx.x == 0) {
        float s = rsum[0];
        #pragma unroll
        for (int ww = 1; ww < 8; ++ww) s += rsum[ww];
        atomicAdd(&out[16384], s);
    }
    __syncthreads();   // rsum dead before smem reuse
}

// ============ 64-row GEMM body (depth-4 B, setprio, keep-alives) ========
__device__ __forceinline__ half8_t ldB(const _Float16* __restrict__ p, int kq) {
    return *(const half8_t*)(p + (size_t)kq * (MTOT * 8));
}

__device__ __forceinline__ void stage_q(
    const _Float16* __restrict__ Wf, _Float16* __restrict__ wlds,
    const int nbb, const int q, const int w, const int lane)
{
    #pragma unroll
    for (int r = 0; r < 8; ++r) {
        const int unit = r * 512 + w * 64 + lane;        // 0..4095 (16B)
        const int s = unit >> 10, off = unit & 1023;
        const _Float16* src = Wf + (size_t)(4 * nbb + s) * 32768
                            + (size_t)q * 8192 + (size_t)off * 8;
        _Float16* dst = wlds + (size_t)unit * 8;
        __builtin_amdgcn_global_load_lds(
            (const __attribute__((address_space(1))) void*)src,
            (__attribute__((address_space(3))) void*)dst, 16, 0, 0);
    }
}

// One k-step: 4 A ds_reads feed 4|8 MFMAs (setprio-wrapped); reload used
// B set <- kb+4 and PIN it live (prevents rematerialization, R18).
template<bool HAS2>
__device__ __forceinline__ void kstep512(
    const _Float16* __restrict__ wlds, const _Float16* const (&bp)[2],
    half8_t (&bb)[2], f32x4 (&acc)[2][4],
    const int lane, const int quad, const int kb, const int j)
{
    half8_t a[4];
    #pragma unroll
    for (int s = 0; s < 4; ++s)
        a[s] = *(const half8_t*)(wlds + (size_t)s * 8192 + (size_t)(j * 64 + lane) * 8);
    __builtin_amdgcn_s_setprio(1);
    #pragma unroll
    for (int s = 0; s < 4; ++s) {
        acc[0][s] = __builtin_amdgcn_mfma_f32_16x16x32_f16(a[s], bb[0], acc[0][s], 0, 0, 0);
        if (HAS2)
            acc[1][s] = __builtin_amdgcn_mfma_f32_16x16x32_f16(a[s], bb[1], acc[1][s], 0, 0, 0);
    }
    __builtin_amdgcn_s_setprio(0);
    if (kb + 4 < 64) {                 // depth-4: reload for kb+4
        const int kq = (kb + 4) * 4 + quad;
        bb[0] = ldB(bp[0], kq);
        asm volatile("" : "+v"(bb[0]));          // pin live (no remat)
        if (HAS2) {
            bb[1] = ldB(bp[1], kq);
            asm volatile("" : "+v"(bb[1]));
        }
    }
}

template<bool HAS2>
__device__ __forceinline__ void gemm64s_run(
    const _Float16* __restrict__ Wf, const _Float16* __restrict__ spk,
    _Float16* __restrict__ I, _Float16* __restrict__ wlds,
    const int (&mt)[2], const int nbb, const int row_base,
    const int w, const int lane, const int quad, const int mi,
    const bool st)
{
    const _Float16* bp[2];
    bp[0] = spk + ((size_t)mt[0] * 16 + mi) * 8;
    bp[1] = spk + ((size_t)mt[1] * 16 + mi) * 8;

    // depth-4 B preload kb=0..3 FIRST (oldest in vmcnt order): the stage
    // drain at the first __syncthreads completes them for free.
    half8_t B0[2], B1[2], B2[2], B3[2];
    B0[0] = ldB(bp[0],      quad);
    B1[0] = ldB(bp[0],  4 + quad);
    B2[0] = ldB(bp[0],  8 + quad);
    B3[0] = ldB(bp[0], 12 + quad);
    asm volatile("" : "+v"(B0[0]), "+v"(B1[0]), "+v"(B2[0]), "+v"(B3[0]));
    if (HAS2) {
        B0[1] = ldB(bp[1],      quad);
        B1[1] = ldB(bp[1],  4 + quad);
        B2[1] = ldB(bp[1],  8 + quad);
        B3[1] = ldB(bp[1], 12 + quad);
        asm volatile("" : "+v"(B0[1]), "+v"(B1[1]), "+v"(B2[1]), "+v"(B3[1]));
    }

    stage_q(Wf, wlds, nbb, 0, w, lane);
    __syncthreads();

    f32x4 acc[2][4];
    #pragma unroll
    for (int u = 0; u < 2; ++u) {
        #pragma unroll
        for (int s = 0; s < 4; ++s) acc[u][s] = (f32x4){0, 0, 0, 0};
    }

    #pragma unroll 1
    for (int q = 0; q < 4; ++q) {
        #pragma unroll
        for (int j = 0; j < 16; j += 4) {
            kstep512<HAS2>(wlds, bp, B0, acc, lane, quad, q * 16 + j,     j);
            kstep512<HAS2>(wlds, bp, B1, acc, lane, quad, q * 16 + j + 1, j + 1);
            kstep512<HAS2>(wlds, bp, B2, acc, lane, quad, q * 16 + j + 2, j + 2);
            kstep512<HAS2>(wlds, bp, B3, acc, lane, quad, q * 16 + j + 3, j + 3);
        }
        __syncthreads();
        if (q < 3) {
            stage_q(Wf, wlds, nbb, q + 1, w, lane);
            __syncthreads();
        }
    }

    #pragma unroll
    for (int s = 0; s < 4; ++s) {
        const int n0 = row_base + s * 16 + quad * 4;
        const size_t obase = (size_t)(n0 >> 3) * (MTOT * 8) + (n0 & 7);
        #pragma unroll
        for (int u = 0; u < 2; ++u) {
            if (u == 0 && !st) continue;
            if (u == 1 && !HAS2) continue;
            half4_t h;
            #pragma unroll
            for (int r = 0; r < 4; ++r) h[r] = (_Float16)acc[u][s][r];
            *(half4_t*)(I + obase + (size_t)(mt[u] * 16 + mi) * 8) = h;
        }
    }
}

template<int NCHUNK>
__device__ __forceinline__ void gemm64s_body(
    const int bid, const _Float16* __restrict__ Wf,
    const _Float16* __restrict__ spk, _Float16* __restrict__ I,
    _Float16* __restrict__ wlds)
{
    const int tid  = threadIdx.x;
    const int lane = tid & 63;
    const int w    = tid >> 6;            // wave 0..7
    const int mi   = lane & 15;
    const int quad = lane >> 4;
    const int chunk = bid % NCHUNK;
    const int rest  = bid / NCHUNK;
    const int msl   = rest & 1;
    const int nbb   = rest >> 1;
    const int row_base = nbb * 64;
    const int jt     = (200 - chunk + NCHUNK - 1) / NCHUNK;
    const int jh     = (jt + 1) >> 1;
    const int jbase  = msl ? jh : 0;
    const int jcount = msl ? (jt - jh) : jh;
    const int rem    = jcount - 8;
    const bool has2  = (w < rem);
    const int r2     = rem > 0 ? rem : 0;
    const bool st    = has2 || (w + r2) < jcount;
    int jl_start = jbase + (has2 ? 2 * w : w + r2);
    const int jmax = jbase + jcount - 1;
    if (jl_start > jmax) jl_start = jmax;

    int mt[2];
    #pragma unroll
    for (int u = 0; u < 2; ++u) {
        int jl = jl_start + u;
        if (jl > jmax) jl = jmax;
        mt[u] = chunk + NCHUNK * jl;
    }

    if (has2) gemm64s_run<true >(Wf, spk, I, wlds, mt, nbb, row_base, w, lane, quad, mi, true);
    else      gemm64s_run<false>(Wf, spk, I, wlds, mt, nbb, row_base, w, lane, quad, mi, st);
}

// ==================== THE MEGA KERNEL (cooperative) =====================
__global__ __launch_bounds__(512, 4) void snn_mega_kernel(
    const float* __restrict__ x, const float* __restrict__ noise,
    const float* __restrict__ W0, const float* __restrict__ b0,
    const float* __restrict__ W1, const float* __restrict__ b1,
    const float* __restrict__ W2, const float* __restrict__ b2,
    _Float16* __restrict__ R0, _Float16* __restrict__ R1,
    _Float16* __restrict__ Ib, float* __restrict__ out)
{
    __shared__ _Float16 smem[32768];          // 64 KB, reused each phase
    __shared__ int s_k;
    const int blk = blockIdx.x;               // 0..511

    if (threadIdx.x == 0) {                   // invocation ticket -> target
        const int v = __hip_atomic_fetch_add(&g_inv, 1, __ATOMIC_RELAXED,
                                             __HIP_MEMORY_SCOPE_AGENT);
        s_k = (v >> 9) + 1;                   // 512 tickets per launch
    }
    __syncthreads();
    const int tgt = 64 * s_k;                 // per-stripe arrival target

    // E: encode -> R0 (200 blks) ; convW0 -> R1 (128 blks)
    if (blk < 200)      encode512_body(blk, x, noise, R0, out, smem);
    else if (blk < 328) convw512_body(blk - 200, W0, R1);
    gate(0, tgt);
    // G0: gemm0(R1, R0 -> I), all 512 blocks
    gemm64s_body<8>(blk, R1, R0, Ib, smem);
    gate(1, tgt);
    // S0: scan0 I->R1 (128 blks) ; convW1 -> R0 (128 blks)
    if (blk < 128)      scan512_body(blk, Ib, b0, R1, out, 0, (float*)smem);
    else if (blk < 256) convw512_body(blk - 128, W1, R0);
    gate(2, tgt);
    // G1: gemm1(R0, R1 -> I)
    gemm64s_body<8>(blk, R0, R1, Ib, smem);
    gate(3, tgt);
    // S1: scan1 I->R0 (128 blks) ; convW2 -> R1 (32 blks)
    if (blk < 128)      scan512_body(blk, Ib, b1, R0, out, 0, (float*)smem);
    else if (blk < 160) convw512_body(blk - 128, W2, R1);
    gate(4, tgt);
    // G2: gemm2(R1, R0 -> I), 256 blocks
    if (blk < 256) gemm64s_body<16>(blk, R1, R0, Ib, smem);
    gate(5, tgt);
    // S2: scan2 -> out (32 blks)
    if (blk < 32) scan512_body(blk, Ib, b2, nullptr, out, 1, (float*)smem);
}

// =================== legacy kernels (fallback path) =====================
__global__ __launch_bounds__(512, 4) void snn_enc512_kernel(
    const float* __restrict__ x, const float* __restrict__ noise,
    _Float16* __restrict__ spk0, float* __restrict__ out,
    const float* __restrict__ W, _Float16* __restrict__ Wf)
{
    __shared__ _Float16 smem[32768];
    if (blockIdx.x < 200) encode512_body(blockIdx.x, x, noise, spk0, out, smem);
    else                  convw512_body(blockIdx.x - 200, W, Wf);
}

__global__ __launch_bounds__(512, 4) void snn_scan_convw512_kernel(
    const _Float16* __restrict__ I, const float* __restrict__ bias,
    _Float16* __restrict__ spk_out, float* __restrict__ out,
    const int scan_blocks, const float* __restrict__ W,
    _Float16* __restrict__ Wf)
{
    __shared__ float rsum[8];
    if ((int)blockIdx.x < scan_blocks)
        scan512_body(blockIdx.x, I, bias, spk_out, out, 0, rsum);
    else
        convw512_body(blockIdx.x - scan_blocks, W, Wf);
}

__global__ __launch_bounds__(512, 4) void snn_scan512_kernel(
    const _Float16* __restrict__ I, const float* __restrict__ bias,
    float* __restrict__ out)
{
    __shared__ float rsum[8];
    scan512_body(blockIdx.x, I, bias, nullptr, out, 1, rsum);
}

template<int NCHUNK>
__global__ __launch_bounds__(512, 4) void snn_gemm64s_kernel(
    const _Float16* __restrict__ Wf, const _Float16* __restrict__ spk,
    _Float16* __restrict__ I)
{
    __shared__ _Float16 wlds[32768];
    gemm64s_body<NCHUNK>(blockIdx.x, Wf, spk, I, wlds);
}

extern "C" void kernel_launch(void* const* d_in, const int* in_sizes, int n_in,
                              void* d_out, int out_size, void* d_ws, size_t ws_size,
                              hipStream_t stream) {
    // setup_inputs() dict order: x, noise, time_steps, W0, b0, W1, b1, W2, b2
    const float* x     = (const float*)d_in[0];
    const float* noise = (const float*)d_in[1];
    const float* W0 = (const float*)d_in[3];
    const float* b0 = (const float*)d_in[4];
    const float* W1 = (const float*)d_in[5];
    const float* b1 = (const float*)d_in[6];
    const float* W2 = (const float*)d_in[7];
    const float* b2 = (const float*)d_in[8];
    float* out = (float*)d_out;

    _Float16* R0 = (_Float16*)((char*)d_ws + R0_OFF);
    _Float16* R1 = (_Float16*)((char*)d_ws + R1_OFF);
    _Float16* Ib = (_Float16*)((char*)d_ws + I_OFF);

    // Cooperative residency required by the custom gates: 2 blocks/CU.
    int maxb = 0;
    hipError_t oe = hipOccupancyMaxActiveBlocksPerMultiprocessor(
        &maxb, (const void*)snn_mega_kernel, 512, 0);

    if (oe == hipSuccess && maxb >= 2) {
        void* args[] = {(void*)&x, (void*)&noise,
                        (void*)&W0, (void*)&b0, (void*)&W1, (void*)&b1,
                        (void*)&W2, (void*)&b2,
                        (void*)&R0, (void*)&R1, (void*)&Ib, (void*)&out};
        hipLaunchCooperativeKernel((const void*)snn_mega_kernel,
                                   dim3(512), dim3(512), args, 0, stream);
    } else {
        // Legacy 7-launch path
        snn_enc512_kernel<<<dim3(328), dim3(512), 0, stream>>>(x, noise, R0, out, W0, R1);
        snn_gemm64s_kernel<8><<<dim3(512), dim3(512), 0, stream>>>(R1, R0, Ib);
        snn_scan_convw512_kernel<<<dim3(256), dim3(512), 0, stream>>>(Ib, b0, R1, out, 128, W1, R0);
        snn_gemm64s_kernel<8><<<dim3(512), dim3(512), 0, stream>>>(R0, R1, Ib);
        snn_scan_convw512_kernel<<<dim3(160), dim3(512), 0, stream>>>(Ib, b1, R0, out, 128, W2, R1);
        snn_gemm64s_kernel<16><<<dim3(256), dim3(512), 0, stream>>>(R1, R0, Ib);
        snn_scan512_kernel<<<dim3(32), dim3(512), 0, stream>>>(Ib, b2, out);
    }

    (void)in_sizes; (void)n_in; (void)out_size; (void)ws_size;
}

// Round 10
// 250.153 us; speedup vs baseline: 1.1926x; 1.1926x over previous
//
#include <hip/hip_runtime.h>
#include <hip/hip_cooperative_groups.h>

// SNN 2048->2048->2048->512, T=100, batch 32, LIF.
// R19 = R17 mega-kernel (proven 245.7us: grid.sync boundaries, per-block
// scan atomic, depth-4 B code) with R18's regressions reverted (custom
// gates, keep-alives, setprio all removed) + two load-balance changes:
//  1) CONSOLIDATED E PHASE (runtime ws_size-gated): all three weight
//     conversions run in E (200 enc + 128 cw0 + 128 cw1 + 32 cw2 = 488
//     of 512 blocks busy; was 328). S0/S1 become pure scans (were
//     max(scan, convw)). Needs W1F (8MB) + W2F (2MB) regions: total
//     49,807,360 B; falls back to exact R17 schedule if ws too small.
//  2) A-PRESTAGE under scan: during S0/S1 every block issues its next-
//     GEMM quarter-0 stage_q before the gate (scan blocks after their
//     scan; idle blocks immediately). The gate's vmcnt drain completes
//     them free; G1/G2 run a PRE path that skips the initial stage+drain.
//     Sources (W1F/W2F) stable since E, two gates earlier. smem WAR-free.
//
// Unified "octet-blocked" layout (pitch MTOT) for spikes AND I:
//   half_idx(v, m) = ((v>>3)*MTOT + m)*8 + (v&7)
// ws regions: R0 0 | R1 13107200 | I 26214400 | W1F 39321600 | W2F 47710208
// cons phases: E{enc->R0,cw0->R1,cw1->W1F,cw2->W2F} | G0(R1,R0->I) |
//   S0{scan->R1 + prestage} | G1(W1F,R1->I) PRE | S1{scan->R0 + prestage}
//   | G2(W2F,R0->I) PRE | S2->out
#define T_STEPS 100
#define MTOT    3200
#define R0_OFF  0
#define R1_OFF  13107200
#define I_OFF   26214400
#define W1F_OFF 39321600
#define W2F_OFF 47710208
#define WS_CONS 49807360ULL

typedef _Float16 half8_t __attribute__((ext_vector_type(8)));
typedef _Float16 half4_t __attribute__((ext_vector_type(4)));
typedef float    f32x4   __attribute__((ext_vector_type(4)));

// ============ encode, 512-thr, 64KB XOR-swizzled LDS ====================
__device__ __forceinline__ void encode512_body(
    int blk, const float* __restrict__ x, const float* __restrict__ noise,
    _Float16* __restrict__ spk0, float* __restrict__ out, _Float16* smem)
{
    if (blk == 0 && threadIdx.x == 0) out[16384] = 0.0f;  // runs first
    const int tid  = threadIdx.x;
    const int m0   = blk * 16;
    const int koct = tid & 255;
    const int mlh  = tid >> 8;
    half8_t* lds = (half8_t*)smem;       // [16][256]
    #pragma unroll
    for (int mlq = 0; mlq < 8; ++mlq) {
        const int ml = mlq * 2 + mlh;
        const int m  = m0 + ml;
        const int t = m >> 5, b = m & 31;
        const float4 x1 = *(const float4*)(x + b * 2048 + koct * 8);
        const float4 x2 = *(const float4*)(x + b * 2048 + koct * 8 + 4);
        const float4 n1 = *(const float4*)(noise + (size_t)t * 65536 + b * 2048 + koct * 8);
        const float4 n2 = *(const float4*)(noise + (size_t)t * 65536 + b * 2048 + koct * 8 + 4);
        const float xr[8] = {x1.x,x1.y,x1.z,x1.w,x2.x,x2.y,x2.z,x2.w};
        const float nz[8] = {n1.x,n1.y,n1.z,n1.w,n2.x,n2.y,n2.z,n2.w};
        half8_t sp;
        #pragma unroll
        for (int q = 0; q < 8; ++q) {
            const float r = fminf(fmaxf(xr[q], 0.0f), 1.0f);
            sp[q] = (nz[q] < r) ? (_Float16)1.0f : (_Float16)0.0f;
        }
        lds[ml * 256 + (koct ^ ml)] = sp;
    }
    __syncthreads();
    #pragma unroll
    for (int r = 0; r < 8; ++r) {        // lanes: ml fast -> 256B contiguous
        const int ml  = tid & 15;
        const int oct = r * 32 + (tid >> 4);
        *(half8_t*)(spk0 + ((size_t)oct * MTOT + m0 + ml) * 8)
            = lds[ml * 256 + (oct ^ ml)];
    }
    __syncthreads();                     // smem dead before phase reuse
}

// ============ convw, 512-thr: W fp32 -> fp16 A-frag swizzled ============
__device__ __forceinline__ void convw512_body(
    int cblk, const float* __restrict__ W, _Float16* __restrict__ Wf)
{
    const int koct = threadIdx.x & 255;
    const int rh   = threadIdx.x >> 8;
    #pragma unroll
    for (int r = 0; r < 8; ++r) {
        const int row = cblk * 16 + rh * 8 + r;
        const float* wp = W + (size_t)row * 2048 + koct * 8;
        const float4 f1 = *(const float4*)(wp);
        const float4 f2 = *(const float4*)(wp + 4);
        half8_t h = {(_Float16)f1.x,(_Float16)f1.y,(_Float16)f1.z,(_Float16)f1.w,
                     (_Float16)f2.x,(_Float16)f2.y,(_Float16)f2.z,(_Float16)f2.w};
        const size_t idx = (size_t)(row >> 4) * 32768
                         + ((size_t)((koct >> 2) * 64 + (koct & 3) * 16 + (row & 15))) * 8;
        *(half8_t*)(Wf + idx) = h;
    }
}

// ============ scan, 512-thr, per-BLOCK single atomic ====================
__device__ __forceinline__ void scan512_body(
    int blk, const _Float16* __restrict__ I, const float* __restrict__ bias,
    _Float16* __restrict__ spk_out, float* __restrict__ out,
    const int is_last, float* rsum)
{
    const int gid = blk * 512 + threadIdx.x;
    const int j   = gid & 7;
    const int b   = (gid >> 3) & 31;
    const int oct = gid >> 8;
    const int n   = oct * 8 + j;
    const float bi = bias[n];
    const size_t nbase = (size_t)oct * (MTOT * 8) + j;
    float mem = 0.f, syn = 0.f, osum = 0.f, cnt = 0.f;
    #pragma unroll 4
    for (int t = 0; t < T_STEPS; ++t) {
        const int m = t * 32 + b;
        const float Iv = (float)I[nbase + (size_t)m * 8] + bi;
        syn = syn + (-syn / 5.0f + Iv);
        mem = mem + (-mem / 20.0f + syn);
        const float sv = (mem >= 1.0f) ? 1.0f : 0.0f;
        mem = (sv != 0.0f) ? 0.0f : mem;       // reset
        mem = (mem > 0.0f) ? mem : 0.0f;       // clamp negatives
        cnt += sv; osum += sv;
        if (!is_last) spk_out[nbase + (size_t)m * 8] = (_Float16)sv;
    }
    if (is_last) out[b * 512 + n] = osum * 0.01f;    // mean over T
    // wave reduce -> LDS -> one atomic per block (G12)
    float c = cnt;
    #pragma unroll
    for (int s2 = 1; s2 < 64; s2 <<= 1) c += __shfl_xor(c, s2);
    const int wid = threadIdx.x >> 6;
    if ((threadIdx.x & 63) == 0) rsum[wid] = c;
    __syncthreads();
    if (threadIdx.x == 0) {
        float s = rsum[0];
        #pragma unroll
        for (int ww = 1; ww < 8; ++ww) s += rsum[ww];
        atomicAdd(&out[16384], s);
    }
    __syncthreads();   // rsum dead before smem reuse
}

// ============ 64-row GEMM body (R17 structure; PRE = prestaged q0) ======
__device__ __forceinline__ half8_t ldB(const _Float16* __restrict__ p, int kq) {
    return *(const half8_t*)(p + (size_t)kq * (MTOT * 8));
}

__device__ __forceinline__ void stage_q(
    const _Float16* __restrict__ Wf, _Float16* __restrict__ wlds,
    const int nbb, const int q, const int w, const int lane)
{
    #pragma unroll
    for (int r = 0; r < 8; ++r) {
        const int unit = r * 512 + w * 64 + lane;        // 0..4095 (16B)
        const int s = unit >> 10, off = unit & 1023;
        const _Float16* src = Wf + (size_t)(4 * nbb + s) * 32768
                            + (size_t)q * 8192 + (size_t)off * 8;
        _Float16* dst = wlds + (size_t)unit * 8;
        __builtin_amdgcn_global_load_lds(
            (const __attribute__((address_space(1))) void*)src,
            (__attribute__((address_space(3))) void*)dst, 16, 0, 0);
    }
}

// One k-step: 4 A ds_reads feed 4|8 MFMAs; reload used B set <- kb+4.
template<bool HAS2>
__device__ __forceinline__ void kstep512(
    const _Float16* __restrict__ wlds, const _Float16* const (&bp)[2],
    half8_t (&bb)[2], f32x4 (&acc)[2][4],
    const int lane, const int quad, const int kb, const int j)
{
    half8_t a[4];
    #pragma unroll
    for (int s = 0; s < 4; ++s)
        a[s] = *(const half8_t*)(wlds + (size_t)s * 8192 + (size_t)(j * 64 + lane) * 8);
    #pragma unroll
    for (int s = 0; s < 4; ++s) {
        acc[0][s] = __builtin_amdgcn_mfma_f32_16x16x32_f16(a[s], bb[0], acc[0][s], 0, 0, 0);
        if (HAS2)
            acc[1][s] = __builtin_amdgcn_mfma_f32_16x16x32_f16(a[s], bb[1], acc[1][s], 0, 0, 0);
    }
    if (kb + 4 < 64) {                 // depth-4: reload for kb+4
        const int kq = (kb + 4) * 4 + quad;
        bb[0] = ldB(bp[0], kq);
        if (HAS2) bb[1] = ldB(bp[1], kq);
    }
}

template<bool HAS2, bool PRE>
__device__ __forceinline__ void gemm64s_run(
    const _Float16* __restrict__ Wf, const _Float16* __restrict__ spk,
    _Float16* __restrict__ I, _Float16* __restrict__ wlds,
    const int (&mt)[2], const int nbb, const int row_base,
    const int w, const int lane, const int quad, const int mi,
    const bool st)
{
    const _Float16* bp[2];
    bp[0] = spk + ((size_t)mt[0] * 16 + mi) * 8;
    bp[1] = spk + ((size_t)mt[1] * 16 + mi) * 8;

    // depth-4 B preload kb=0..3 FIRST (oldest in vmcnt order).
    half8_t B0[2], B1[2], B2[2], B3[2];
    B0[0] = ldB(bp[0],      quad);
    B1[0] = ldB(bp[0],  4 + quad);
    B2[0] = ldB(bp[0],  8 + quad);
    B3[0] = ldB(bp[0], 12 + quad);
    if (HAS2) {
        B0[1] = ldB(bp[1],      quad);
        B1[1] = ldB(bp[1],  4 + quad);
        B2[1] = ldB(bp[1],  8 + quad);
        B3[1] = ldB(bp[1], 12 + quad);
    }

    if (!PRE) {       // PRE: quarter 0 already staged before the gate
        stage_q(Wf, wlds, nbb, 0, w, lane);
        __syncthreads();
    }

    f32x4 acc[2][4];
    #pragma unroll
    for (int u = 0; u < 2; ++u) {
        #pragma unroll
        for (int s = 0; s < 4; ++s) acc[u][s] = (f32x4){0, 0, 0, 0};
    }

    #pragma unroll 1
    for (int q = 0; q < 4; ++q) {
        #pragma unroll
        for (int j = 0; j < 16; j += 4) {
            kstep512<HAS2>(wlds, bp, B0, acc, lane, quad, q * 16 + j,     j);
            kstep512<HAS2>(wlds, bp, B1, acc, lane, quad, q * 16 + j + 1, j + 1);
            kstep512<HAS2>(wlds, bp, B2, acc, lane, quad, q * 16 + j + 2, j + 2);
            kstep512<HAS2>(wlds, bp, B3, acc, lane, quad, q * 16 + j + 3, j + 3);
        }
        __syncthreads();
        if (q < 3) {
            stage_q(Wf, wlds, nbb, q + 1, w, lane);
            __syncthreads();
        }
    }

    #pragma unroll
    for (int s = 0; s < 4; ++s) {
        const int n0 = row_base + s * 16 + quad * 4;
        const size_t obase = (size_t)(n0 >> 3) * (MTOT * 8) + (n0 & 7);
        #pragma unroll
        for (int u = 0; u < 2; ++u) {
            if (u == 0 && !st) continue;
            if (u == 1 && !HAS2) continue;
            half4_t h;
            #pragma unroll
            for (int r = 0; r < 4; ++r) h[r] = (_Float16)acc[u][s][r];
            *(half4_t*)(I + obase + (size_t)(mt[u] * 16 + mi) * 8) = h;
        }
    }
}

template<int NCHUNK, bool PRE>
__device__ __forceinline__ void gemm64s_body(
    const int bid, const _Float16* __restrict__ Wf,
    const _Float16* __restrict__ spk, _Float16* __restrict__ I,
    _Float16* __restrict__ wlds)
{
    const int tid  = threadIdx.x;
    const int lane = tid & 63;
    const int w    = tid >> 6;            // wave 0..7
    const int mi   = lane & 15;
    const int quad = lane >> 4;
    const int chunk = bid % NCHUNK;
    const int rest  = bid / NCHUNK;
    const int msl   = rest & 1;
    const int nbb   = rest >> 1;
    const int row_base = nbb * 64;
    const int jt     = (200 - chunk + NCHUNK - 1) / NCHUNK;
    const int jh     = (jt + 1) >> 1;
    const int jbase  = msl ? jh : 0;
    const int jcount = msl ? (jt - jh) : jh;
    const int rem    = jcount - 8;
    const bool has2  = (w < rem);
    const int r2     = rem > 0 ? rem : 0;
    const bool st    = has2 || (w + r2) < jcount;
    int jl_start = jbase + (has2 ? 2 * w : w + r2);
    const int jmax = jbase + jcount - 1;
    if (jl_start > jmax) jl_start = jmax;

    int mt[2];
    #pragma unroll
    for (int u = 0; u < 2; ++u) {
        int jl = jl_start + u;
        if (jl > jmax) jl = jmax;
        mt[u] = chunk + NCHUNK * jl;
    }

    if (has2) gemm64s_run<true , PRE>(Wf, spk, I, wlds, mt, nbb, row_base, w, lane, quad, mi, true);
    else      gemm64s_run<false, PRE>(Wf, spk, I, wlds, mt, nbb, row_base, w, lane, quad, mi, st);
}

// ==================== THE MEGA KERNEL (cooperative) =====================
__global__ __launch_bounds__(512, 4) void snn_mega_kernel(
    const float* __restrict__ x, const float* __restrict__ noise,
    const float* __restrict__ W0, const float* __restrict__ b0,
    const float* __restrict__ W1, const float* __restrict__ b1,
    const float* __restrict__ W2, const float* __restrict__ b2,
    _Float16* __restrict__ R0, _Float16* __restrict__ R1,
    _Float16* __restrict__ Ib, _Float16* __restrict__ W1F,
    _Float16* __restrict__ W2F, const int cons,
    float* __restrict__ out)
{
    cooperative_groups::grid_group grid = cooperative_groups::this_grid();
    __shared__ _Float16 smem[32768];          // 64 KB, reused each phase
    const int blk = blockIdx.x;               // 0..511
    const int w = threadIdx.x >> 6, lane = threadIdx.x & 63;

    // E: encode -> R0 ; convW0 -> R1 ; [cons: convW1 -> W1F, convW2 -> W2F]
    if (blk < 200)      encode512_body(blk, x, noise, R0, out, smem);
    else if (blk < 328) convw512_body(blk - 200, W0, R1);
    else if (cons && blk < 456) convw512_body(blk - 328, W1, W1F);
    else if (cons && blk < 488) convw512_body(blk - 456, W2, W2F);
    grid.sync();
    // G0: gemm0(R1, R0 -> I), all 512 blocks
    gemm64s_body<8, false>(blk, R1, R0, Ib, smem);
    grid.sync();
    // S0: scan0 I->R1 ; cons: all blocks prestage G1 quarter-0
    if (cons) {
        if (blk < 128) scan512_body(blk, Ib, b0, R1, out, 0, (float*)smem);
        stage_q(W1F, smem, (blk >> 3) >> 1, 0, w, lane);   // G1 nbb
    } else {
        if (blk < 128)      scan512_body(blk, Ib, b0, R1, out, 0, (float*)smem);
        else if (blk < 256) convw512_body(blk - 128, W1, R0);
    }
    grid.sync();
    // G1
    if (cons) gemm64s_body<8, true >(blk, W1F, R1, Ib, smem);
    else      gemm64s_body<8, false>(blk, R0,  R1, Ib, smem);
    grid.sync();
    // S1: scan1 I->R0 ; cons: G2 blocks prestage quarter-0
    if (cons) {
        if (blk < 128) scan512_body(blk, Ib, b1, R0, out, 0, (float*)smem);
        if (blk < 256) stage_q(W2F, smem, (blk >> 4) >> 1, 0, w, lane);  // G2 nbb
    } else {
        if (blk < 128)      scan512_body(blk, Ib, b1, R0, out, 0, (float*)smem);
        else if (blk < 160) convw512_body(blk - 128, W2, R1);
    }
    grid.sync();
    // G2: 256 blocks
    if (blk < 256) {
        if (cons) gemm64s_body<16, true >(blk, W2F, R0, Ib, smem);
        else      gemm64s_body<16, false>(blk, R1,  R0, Ib, smem);
    }
    grid.sync();
    // S2: scan2 -> out (32 blks)
    if (blk < 32) scan512_body(blk, Ib, b2, nullptr, out, 1, (float*)smem);
}

// =================== legacy kernels (fallback path) =====================
__global__ __launch_bounds__(512, 4) void snn_enc512_kernel(
    const float* __restrict__ x, const float* __restrict__ noise,
    _Float16* __restrict__ spk0, float* __restrict__ out,
    const float* __restrict__ W, _Float16* __restrict__ Wf)
{
    __shared__ _Float16 smem[32768];
    if (blockIdx.x < 200) encode512_body(blockIdx.x, x, noise, spk0, out, smem);
    else                  convw512_body(blockIdx.x - 200, W, Wf);
}

__global__ __launch_bounds__(512, 4) void snn_scan_convw512_kernel(
    const _Float16* __restrict__ I, const float* __restrict__ bias,
    _Float16* __restrict__ spk_out, float* __restrict__ out,
    const int scan_blocks, const float* __restrict__ W,
    _Float16* __restrict__ Wf)
{
    __shared__ float rsum[8];
    if ((int)blockIdx.x < scan_blocks)
        scan512_body(blockIdx.x, I, bias, spk_out, out, 0, rsum);
    else
        convw512_body(blockIdx.x - scan_blocks, W, Wf);
}

__global__ __launch_bounds__(512, 4) void snn_scan512_kernel(
    const _Float16* __restrict__ I, const float* __restrict__ bias,
    float* __restrict__ out)
{
    __shared__ float rsum[8];
    scan512_body(blockIdx.x, I, bias, nullptr, out, 1, rsum);
}

template<int NCHUNK>
__global__ __launch_bounds__(512, 4) void snn_gemm64s_kernel(
    const _Float16* __restrict__ Wf, const _Float16* __restrict__ spk,
    _Float16* __restrict__ I)
{
    __shared__ _Float16 wlds[32768];
    gemm64s_body<NCHUNK, false>(blockIdx.x, Wf, spk, I, wlds);
}

extern "C" void kernel_launch(void* const* d_in, const int* in_sizes, int n_in,
                              void* d_out, int out_size, void* d_ws, size_t ws_size,
                              hipStream_t stream) {
    // setup_inputs() dict order: x, noise, time_steps, W0, b0, W1, b1, W2, b2
    const float* x     = (const float*)d_in[0];
    const float* noise = (const float*)d_in[1];
    const float* W0 = (const float*)d_in[3];
    const float* b0 = (const float*)d_in[4];
    const float* W1 = (const float*)d_in[5];
    const float* b1 = (const float*)d_in[6];
    const float* W2 = (const float*)d_in[7];
    const float* b2 = (const float*)d_in[8];
    float* out = (float*)d_out;

    _Float16* R0 = (_Float16*)((char*)d_ws + R0_OFF);
    _Float16* R1 = (_Float16*)((char*)d_ws + R1_OFF);
    _Float16* Ib = (_Float16*)((char*)d_ws + I_OFF);
    const int cons = (ws_size >= WS_CONS) ? 1 : 0;
    _Float16* W1F = cons ? (_Float16*)((char*)d_ws + W1F_OFF) : R0;
    _Float16* W2F = cons ? (_Float16*)((char*)d_ws + W2F_OFF) : R0;

    // Cooperative residency: 2 blocks/CU required.
    int maxb = 0;
    hipError_t oe = hipOccupancyMaxActiveBlocksPerMultiprocessor(
        &maxb, (const void*)snn_mega_kernel, 512, 0);

    if (oe == hipSuccess && maxb >= 2) {
        void* args[] = {(void*)&x, (void*)&noise,
                        (void*)&W0, (void*)&b0, (void*)&W1, (void*)&b1,
                        (void*)&W2, (void*)&b2,
                        (void*)&R0, (void*)&R1, (void*)&Ib,
                        (void*)&W1F, (void*)&W2F, (void*)&cons,
                        (void*)&out};
        hipLaunchCooperativeKernel((const void*)snn_mega_kernel,
                                   dim3(512), dim3(512), args, 0, stream);
    } else {
        // Legacy 7-launch path (R17-equivalent schedule)
        snn_enc512_kernel<<<dim3(328), dim3(512), 0, stream>>>(x, noise, R0, out, W0, R1);
        snn_gemm64s_kernel<8><<<dim3(512), dim3(512), 0, stream>>>(R1, R0, Ib);
        snn_scan_convw512_kernel<<<dim3(256), dim3(512), 0, stream>>>(Ib, b0, R1, out, 128, W1, R0);
        snn_gemm64s_kernel<8><<<dim3(512), dim3(512), 0, stream>>>(R0, R1, Ib);
        snn_scan_convw512_kernel<<<dim3(160), dim3(512), 0, stream>>>(Ib, b1, R0, out, 128, W2, R1);
        snn_gemm64s_kernel<16><<<dim3(256), dim3(512), 0, stream>>>(R1, R0, Ib);
        snn_scan512_kernel<<<dim3(32), dim3(512), 0, stream>>>(Ib, b2, out);
    }

    (void)in_sizes; (void)n_in; (void)out_size; (void)ws_size;
}